// Round 1
// baseline (316.442 us; speedup 1.0000x reference)
//
#include <hip/hip_runtime.h>
#include <math.h>

// Problem constants (fixed by setup_inputs): B=16, N=M=4096, K=64.
#define BB 16
#define NN 4096
#define MM 4096
#define KDIM 64
#define CHUNK 256
#define THREADS 256

// ---------------------------------------------------------------------------
// Chamfer min-distance pass. Grid: (N/256 row-tiles, B, 2 directions).
// Each thread owns one "row" point, loops over all M "col" points staged in
// LDS as float4 (x,y,z,|t|^2). min over squared distances, sqrt once at end,
// block-reduce sum, one atomicAdd per block.
// ---------------------------------------------------------------------------
__global__ __launch_bounds__(THREADS) void chamfer_kernel(
    const float* __restrict__ pred, const float* __restrict__ gt,
    float* __restrict__ out)
{
    const int tile = blockIdx.x;   // 0..15
    const int b    = blockIdx.y;   // 0..15
    const int dir  = blockIdx.z;   // 0: pred->gt, 1: gt->pred
    const float* rows = dir ? gt : pred;
    const float* cols = dir ? pred : gt;
    const int tid = threadIdx.x;
    const int n = tile * THREADS + tid;

    const float* rp = rows + ((size_t)b * NN + n) * 3;
    const float px = rp[0], py = rp[1], pz = rp[2];
    const float p2 = px * px + py * py + pz * pz;
    const float* cb = cols + (size_t)b * MM * 3;

    __shared__ float4 sT[CHUNK];
    float minv = 3.4e38f;

    for (int m0 = 0; m0 < MM; m0 += CHUNK) {
        // cooperative stage: each thread loads one point, computes |t|^2
        const float* tp = cb + (size_t)(m0 + tid) * 3;
        const float tx = tp[0], ty = tp[1], tz = tp[2];
        __syncthreads();   // previous chunk fully consumed
        sT[tid] = make_float4(tx, ty, tz, tx * tx + ty * ty + tz * tz);
        __syncthreads();

        #pragma unroll 8
        for (int j = 0; j < CHUNK; ++j) {
            const float4 t = sT[j];                      // broadcast read
            float c = px * t.x;
            c = fmaf(py, t.y, c);
            c = fmaf(pz, t.z, c);
            const float d2 = fmaf(-2.0f, c, p2 + t.w);   // |p-t|^2, fp32 exact enough
            minv = fminf(minv, d2);
        }
    }

    float dist = sqrtf(fmaxf(minv, 0.0f));

    // block reduction: wave64 shuffle then cross-wave via LDS
    #pragma unroll
    for (int off = 32; off > 0; off >>= 1)
        dist += __shfl_down(dist, off, 64);
    __shared__ float ssum[THREADS / 64];
    const int lane = tid & 63, wid = tid >> 6;
    if (lane == 0) ssum[wid] = dist;
    __syncthreads();
    if (tid == 0) {
        float s = 0.f;
        #pragma unroll
        for (int w = 0; w < THREADS / 64; ++w) s += ssum[w];
        // N == M so both directions use the same scale: 1/(B*N)
        atomicAdd(out, s * (1.0f / ((float)BB * (float)NN)));
    }
}

// ---------------------------------------------------------------------------
// Feature-transform regularizer: per batch b, ||trans@trans^T - I||_F.
// One block per batch; trans[b] (64x64) staged in LDS with stride-68 padding
// (row start stays 16B aligned, kills the stride-256B bank conflict).
// Each thread computes 16 gram entries (i = tid>>2, j = (tid&3) + 4*jj).
// ---------------------------------------------------------------------------
#define RSTRIDE 68
__global__ __launch_bounds__(256) void reg_kernel(
    const float* __restrict__ trans, float* __restrict__ out)
{
    const int b = blockIdx.x;
    const int tid = threadIdx.x;
    __shared__ float sA[KDIM * RSTRIDE];

    const float4* src = (const float4*)(trans + (size_t)b * KDIM * KDIM);
    #pragma unroll
    for (int r = 0; r < 4; ++r) {
        const int idx = r * 256 + tid;       // float4 index, 16 per row
        const int row = idx >> 4;
        const int colv = idx & 15;
        *(float4*)&sA[row * RSTRIDE + colv * 4] = src[idx];
    }
    __syncthreads();

    const int i = tid >> 2;
    float local = 0.f;
    for (int jj = 0; jj < 16; ++jj) {
        const int j = (tid & 3) + jj * 4;
        float acc = 0.f;
        #pragma unroll
        for (int k = 0; k < 16; ++k) {
            const float4 a = *(const float4*)&sA[i * RSTRIDE + k * 4];
            const float4 c = *(const float4*)&sA[j * RSTRIDE + k * 4];
            acc = fmaf(a.x, c.x, acc);
            acc = fmaf(a.y, c.y, acc);
            acc = fmaf(a.z, c.z, acc);
            acc = fmaf(a.w, c.w, acc);
        }
        const float d = acc - (i == j ? 1.0f : 0.0f);
        local = fmaf(d, d, local);
    }

    #pragma unroll
    for (int off = 32; off > 0; off >>= 1)
        local += __shfl_down(local, off, 64);
    __shared__ float ssum[4];
    if ((tid & 63) == 0) ssum[tid >> 6] = local;
    __syncthreads();
    if (tid == 0) {
        const float tot = ssum[0] + ssum[1] + ssum[2] + ssum[3];
        atomicAdd(out, (0.1f / (float)BB) * sqrtf(tot));
    }
}

extern "C" void kernel_launch(void* const* d_in, const int* in_sizes, int n_in,
                              void* d_out, int out_size, void* d_ws, size_t ws_size,
                              hipStream_t stream)
{
    const float* pred  = (const float*)d_in[0];
    const float* gt    = (const float*)d_in[1];
    const float* trans = (const float*)d_in[2];
    float* out = (float*)d_out;

    hipMemsetAsync(out, 0, sizeof(float), stream);

    reg_kernel<<<dim3(BB), dim3(256), 0, stream>>>(trans, out);
    chamfer_kernel<<<dim3(NN / THREADS, BB, 2), dim3(THREADS), 0, stream>>>(pred, gt, out);
}

// Round 2
// 67.100 us; speedup vs baseline: 4.7159x; 4.7159x over previous
//
#include <hip/hip_runtime.h>
#include <math.h>

// Problem constants (fixed by setup_inputs): B=16, N=M=4096, K=64.
#define BB 16
#define NN 4096
#define MM 4096
#define KDIM 64
#define THREADS 256
#define RPT 8                 // row points per thread
#define SLICE 512             // M points per block (one slice)
#define NSLICE (MM / SLICE)   // 8
#define NROWS_TOTAL (2 * BB * NN)   // 131072 rows across both directions

// ---------------------------------------------------------------------------
// Pass A: per (row-tile, M-slice) block, compute min over the slice of
//   v = |t|^2 - 2 p.t   (p^2 added later; sqrt later)
// Each thread owns RPT=8 row points (q = -2p folded in => 3 fma + 1 min per
// pair). Slice staged in LDS as float4(x,y,z,|t|^2); one ds_read_b128
// broadcast feeds 8 rows => VALU-bound.
// Partial mins combined across slices via atomicMin on order-preserving uint.
// ---------------------------------------------------------------------------
__global__ __launch_bounds__(THREADS) void chamfer_min_kernel(
    const float* __restrict__ pred, const float* __restrict__ gt,
    unsigned int* __restrict__ wsmin)
{
    const int bx     = blockIdx.x;
    const int mslice = bx & (NSLICE - 1);
    const int tile   = bx >> 3;            // NSLICE == 8
    const int b      = blockIdx.y;
    const int dir    = blockIdx.z;         // 0: pred->gt, 1: gt->pred
    const float* rows = dir ? gt : pred;
    const float* cols = dir ? pred : gt;
    const int tid = threadIdx.x;

    // Load this thread's 8 row points; fold the -2.
    float qx[RPT], qy[RPT], qz[RPT], mv[RPT];
    const float* rb = rows + ((size_t)b * NN + (size_t)tile * (THREADS * RPT)) * 3;
    #pragma unroll
    for (int k = 0; k < RPT; ++k) {
        const float* rp = rb + (size_t)(k * THREADS + tid) * 3;
        qx[k] = -2.0f * rp[0];
        qy[k] = -2.0f * rp[1];
        qz[k] = -2.0f * rp[2];
        mv[k] = 3.4e38f;
    }

    // Stage the M-slice into LDS with |t|^2 packed in w.
    __shared__ float4 sT[SLICE];
    const float* cbase = cols + ((size_t)b * MM + (size_t)mslice * SLICE) * 3;
    #pragma unroll
    for (int k = 0; k < SLICE / THREADS; ++k) {
        const float* tp = cbase + (size_t)(k * THREADS + tid) * 3;
        const float tx = tp[0], ty = tp[1], tz = tp[2];
        sT[k * THREADS + tid] = make_float4(tx, ty, tz, tx * tx + ty * ty + tz * tz);
    }
    __syncthreads();

    #pragma unroll 4
    for (int j = 0; j < SLICE; ++j) {
        const float4 t = sT[j];            // broadcast, amortized over 8 rows
        #pragma unroll
        for (int k = 0; k < RPT; ++k) {
            float v = fmaf(qx[k], t.x, t.w);
            v = fmaf(qy[k], t.y, v);
            v = fmaf(qz[k], t.z, v);
            mv[k] = fminf(mv[k], v);
        }
    }

    // Publish per-slice partial mins. Order-preserving float->uint map.
    const int rowg = (dir * BB + b) * NN + tile * (THREADS * RPT);
    #pragma unroll
    for (int k = 0; k < RPT; ++k) {
        unsigned int u = __float_as_uint(mv[k]);
        u = (u & 0x80000000u) ? ~u : (u | 0x80000000u);
        atomicMin(&wsmin[rowg + k * THREADS + tid], u);
    }
}

// ---------------------------------------------------------------------------
// Pass B: decode per-row min, add p^2, sqrt, mean-reduce, atomicAdd to out.
// ---------------------------------------------------------------------------
__global__ __launch_bounds__(256) void chamfer_finish_kernel(
    const float* __restrict__ pred, const float* __restrict__ gt,
    const unsigned int* __restrict__ wsmin, float* __restrict__ out)
{
    const int g = blockIdx.x * 256 + threadIdx.x;   // 0 .. 131071
    const int dir = g >> 16;
    const int b   = (g >> 12) & (BB - 1);
    const int n   = g & (NN - 1);
    const float* rows = dir ? gt : pred;
    const float* rp = rows + ((size_t)b * NN + n) * 3;
    const float p2 = rp[0] * rp[0] + rp[1] * rp[1] + rp[2] * rp[2];

    unsigned int u = wsmin[g];
    const unsigned int bts = (u & 0x80000000u) ? (u & 0x7fffffffu) : ~u;
    float d = sqrtf(fmaxf(p2 + __uint_as_float(bts), 0.0f));

    #pragma unroll
    for (int off = 32; off > 0; off >>= 1)
        d += __shfl_down(d, off, 64);
    __shared__ float ssum[4];
    const int tid = threadIdx.x;
    if ((tid & 63) == 0) ssum[tid >> 6] = d;
    __syncthreads();
    if (tid == 0) {
        const float s = ssum[0] + ssum[1] + ssum[2] + ssum[3];
        atomicAdd(out, s * (1.0f / ((float)BB * (float)NN)));
    }
}

// ---------------------------------------------------------------------------
// Feature-transform regularizer: per batch b, ||trans@trans^T - I||_F.
// One block per batch; 64x64 staged in LDS, stride-68 padding.
// ---------------------------------------------------------------------------
#define RSTRIDE 68
__global__ __launch_bounds__(256) void reg_kernel(
    const float* __restrict__ trans, float* __restrict__ out)
{
    const int b = blockIdx.x;
    const int tid = threadIdx.x;
    __shared__ float sA[KDIM * RSTRIDE];

    const float4* src = (const float4*)(trans + (size_t)b * KDIM * KDIM);
    #pragma unroll
    for (int r = 0; r < 4; ++r) {
        const int idx = r * 256 + tid;       // float4 index, 16 per row
        const int row = idx >> 4;
        const int colv = idx & 15;
        *(float4*)&sA[row * RSTRIDE + colv * 4] = src[idx];
    }
    __syncthreads();

    const int i = tid >> 2;
    float local = 0.f;
    for (int jj = 0; jj < 16; ++jj) {
        const int j = (tid & 3) + jj * 4;
        float acc = 0.f;
        #pragma unroll
        for (int k = 0; k < 16; ++k) {
            const float4 a = *(const float4*)&sA[i * RSTRIDE + k * 4];
            const float4 c = *(const float4*)&sA[j * RSTRIDE + k * 4];
            acc = fmaf(a.x, c.x, acc);
            acc = fmaf(a.y, c.y, acc);
            acc = fmaf(a.z, c.z, acc);
            acc = fmaf(a.w, c.w, acc);
        }
        const float d = acc - (i == j ? 1.0f : 0.0f);
        local = fmaf(d, d, local);
    }

    #pragma unroll
    for (int off = 32; off > 0; off >>= 1)
        local += __shfl_down(local, off, 64);
    __shared__ float ssum[4];
    if ((tid & 63) == 0) ssum[tid >> 6] = local;
    __syncthreads();
    if (tid == 0) {
        const float tot = ssum[0] + ssum[1] + ssum[2] + ssum[3];
        atomicAdd(out, (0.1f / (float)BB) * sqrtf(tot));
    }
}

extern "C" void kernel_launch(void* const* d_in, const int* in_sizes, int n_in,
                              void* d_out, int out_size, void* d_ws, size_t ws_size,
                              hipStream_t stream)
{
    const float* pred  = (const float*)d_in[0];
    const float* gt    = (const float*)d_in[1];
    const float* trans = (const float*)d_in[2];
    float* out = (float*)d_out;
    unsigned int* wsmin = (unsigned int*)d_ws;   // 131072 uints = 512 KB

    hipMemsetAsync(out, 0, sizeof(float), stream);
    hipMemsetAsync(wsmin, 0xFF, (size_t)NROWS_TOTAL * sizeof(unsigned int), stream);

    reg_kernel<<<dim3(BB), dim3(256), 0, stream>>>(trans, out);

    // grid.x = row-tiles (NN / (THREADS*RPT) = 2) * NSLICE (8) = 16
    chamfer_min_kernel<<<dim3((NN / (THREADS * RPT)) * NSLICE, BB, 2),
                         dim3(THREADS), 0, stream>>>(pred, gt, wsmin);
    chamfer_finish_kernel<<<dim3(NROWS_TOTAL / 256), dim3(256), 0, stream>>>(
        pred, gt, wsmin, out);
}

// Round 3
// 32.800 us; speedup vs baseline: 9.6477x; 2.0458x over previous
//
#include <hip/hip_runtime.h>
#include <math.h>

// Problem constants: B=16, N=M=4096, K=64.
#define BB 16
#define NN 4096
#define MM 4096
#define CHUNK_COLS 2048
#define NCHUNK (MM / CHUNK_COLS)

typedef __attribute__((ext_vector_type(8))) short bf16x8;
typedef __attribute__((ext_vector_type(16))) float f32x16;

static __device__ inline unsigned short f2bf(float f) {
    unsigned int u = __float_as_uint(f);
    return (unsigned short)((u + 0x7FFFu + ((u >> 16) & 1u)) >> 16);  // RNE
}
static __device__ inline bf16x8 bzero() {
    bf16x8 z;
    #pragma unroll
    for (int i = 0; i < 8; ++i) z[i] = 0;
    return z;
}
static __device__ inline f32x16 fzero() {
    f32x16 z;
    #pragma unroll
    for (int i = 0; i < 16; ++i) z[i] = 0.f;
    return z;
}

// ---------------------------------------------------------------------------
// Chamfer via MFMA. d2 = dot_{K=5}([-2px,-2py,-2pz,p2,1],[tx,ty,tz,1,t2]).
// One v_mfma_f32_32x32x16_bf16 = 1024 complete d2 values; epilogue = running
// min3 over col-tiles. Wave owns 64 rows (2 A-frags); M streamed via LDS in
// 2 chunks of 2048 packed cols. Row-min finished through an LDS transpose.
// Grid: (N/256, B, 2 directions), block 256 (4 waves).
// ---------------------------------------------------------------------------
__global__ __launch_bounds__(256, 4) void chamfer_kernel(
    const float* __restrict__ pred, const float* __restrict__ gt,
    float* __restrict__ out)
{
    __shared__ __align__(16) float smem[8832];  // union: stage 32KB | epilogue 34.5KB
    __shared__ float ssum[4];

    const int tid  = threadIdx.x;
    const int lane = tid & 63;
    const int w    = tid >> 6;
    const int li   = lane & 31;
    const int hi   = lane >> 5;
    const int b    = blockIdx.y;
    const int dir  = blockIdx.z;
    const float* rows = dir ? gt : pred;
    const float* cols = dir ? pred : gt;
    const float* rb = rows + (size_t)b * NN * 3;
    const float* cb = cols + (size_t)b * MM * 3;

    // A fragments: rows r0..r0+63. Lanes 0-31 carry k=0..7 (only k=0..4 used);
    // lanes 32-63 carry k=8..15 (all zero).
    const int r0 = blockIdx.x * 256 + w * 64;
    bf16x8 A0 = bzero(), A1 = bzero();
    if (lane < 32) {
        #pragma unroll
        for (int f = 0; f < 2; ++f) {
            const float* rp = rb + (size_t)(r0 + f * 32 + li) * 3;
            const float px = rp[0], py = rp[1], pz = rp[2];
            const float p2 = px * px + py * py + pz * pz;
            bf16x8 fr = bzero();
            fr[0] = (short)f2bf(-2.f * px);
            fr[1] = (short)f2bf(-2.f * py);
            fr[2] = (short)f2bf(-2.f * pz);
            fr[3] = (short)f2bf(p2);
            fr[4] = (short)0x3F80;          // 1.0
            if (f == 0) A0 = fr; else A1 = fr;
        }
    }

    float mv0[16], mv1[16];
    #pragma unroll
    for (int r = 0; r < 16; ++r) { mv0[r] = 3.4e38f; mv1[r] = 3.4e38f; }

    uint4* sB = (uint4*)smem;
    const bf16x8* sBf = (const bf16x8*)smem;

    for (int ch = 0; ch < NCHUNK; ++ch) {
        __syncthreads();                     // previous chunk fully consumed
        #pragma unroll
        for (int i = 0; i < CHUNK_COLS / 256; ++i) {
            const int c = i * 256 + tid;
            const float* tp = cb + (size_t)(ch * CHUNK_COLS + c) * 3;
            const float tx = tp[0], ty = tp[1], tz = tp[2];
            const float t2 = tx * tx + ty * ty + tz * tz;
            uint4 pk;
            pk.x = (unsigned)f2bf(tx) | ((unsigned)f2bf(ty) << 16);  // k0,k1
            pk.y = (unsigned)f2bf(tz) | (0x3F80u << 16);             // k2,k3=1.0
            pk.z = (unsigned)f2bf(t2);                               // k4,k5=0
            pk.w = 0u;
            sB[c] = pk;
        }
        __syncthreads();

        #pragma unroll 2
        for (int jt = 0; jt < CHUNK_COLS / 64; ++jt) {
            bf16x8 b1 = bzero(), b2 = bzero();
            if (lane < 32) {                 // lanes>=32 supply k=8..15 = 0
                b1 = sBf[jt * 64 + li];
                b2 = sBf[jt * 64 + 32 + li];
            }
            f32x16 a11 = __builtin_amdgcn_mfma_f32_32x32x16_bf16(A0, b1, fzero(), 0, 0, 0);
            f32x16 a12 = __builtin_amdgcn_mfma_f32_32x32x16_bf16(A0, b2, fzero(), 0, 0, 0);
            #pragma unroll
            for (int r = 0; r < 16; ++r)
                mv0[r] = fminf(fminf(a11[r], a12[r]), mv0[r]);   // -> v_min3_f32
            f32x16 a21 = __builtin_amdgcn_mfma_f32_32x32x16_bf16(A1, b1, fzero(), 0, 0, 0);
            f32x16 a22 = __builtin_amdgcn_mfma_f32_32x32x16_bf16(A1, b2, fzero(), 0, 0, 0);
            #pragma unroll
            for (int r = 0; r < 16; ++r)
                mv1[r] = fminf(fminf(a21[r], a22[r]), mv1[r]);
        }
    }

    // Epilogue: rows live across lanes (acc row=(r&3)+8*(r>>2)+4*hi, col=li).
    // Transpose via LDS (stride 68 kills the stride-64 conflict), then one
    // thread per row reduces the 32 col-residue partial mins.
    __syncthreads();
    {
        float* wb = smem + w * 2208 + li * 68;
        #pragma unroll
        for (int q = 0; q < 4; ++q) {
            const int rl = q * 8 + hi * 4;
            *(float4*)&wb[rl]      = make_float4(mv0[4*q], mv0[4*q+1], mv0[4*q+2], mv0[4*q+3]);
            *(float4*)&wb[rl + 32] = make_float4(mv1[4*q], mv1[4*q+1], mv1[4*q+2], mv1[4*q+3]);
        }
    }
    __syncthreads();

    const float* rbm = smem + (tid >> 6) * 2208 + (tid & 63);
    float m = 3.4e38f;
    #pragma unroll
    for (int c = 0; c < 32; ++c) m = fminf(m, rbm[c * 68]);
    float d = sqrtf(fmaxf(m, 0.0f));

    #pragma unroll
    for (int off = 32; off > 0; off >>= 1)
        d += __shfl_down(d, off, 64);
    if (lane == 0) ssum[w] = d;
    __syncthreads();
    if (tid == 0) {
        const float s = ssum[0] + ssum[1] + ssum[2] + ssum[3];
        atomicAdd(out, s * (1.0f / ((float)BB * (float)NN)));
    }
}

// ---------------------------------------------------------------------------
// Regularizer via MFMA: G = T.T^T (64x64, K=64 = 4 chained 32x32x16 MFMAs per
// output tile). One wave per batch. A-frag(fi,s) == B-frag(fj,s) == bf16 of
// T[tile*32+li][s*16+hi*8+e]. fp32 accumulate; then sum (G-I)^2, sqrt, add.
// ---------------------------------------------------------------------------
__global__ __launch_bounds__(64) void reg_kernel(
    const float* __restrict__ trans, float* __restrict__ out)
{
    const int b = blockIdx.x;
    const int lane = threadIdx.x;
    const int hi = lane >> 5, li = lane & 31;
    const float* T = trans + (size_t)b * 64 * 64;

    bf16x8 frag[2][4];
    #pragma unroll
    for (int h = 0; h < 2; ++h) {
        #pragma unroll
        for (int s = 0; s < 4; ++s) {
            const float* rp = T + (size_t)(h * 32 + li) * 64 + s * 16 + hi * 8;
            const float4 u0 = *(const float4*)rp;
            const float4 u1 = *(const float4*)(rp + 4);
            bf16x8 fr;
            fr[0] = (short)f2bf(u0.x); fr[1] = (short)f2bf(u0.y);
            fr[2] = (short)f2bf(u0.z); fr[3] = (short)f2bf(u0.w);
            fr[4] = (short)f2bf(u1.x); fr[5] = (short)f2bf(u1.y);
            fr[6] = (short)f2bf(u1.z); fr[7] = (short)f2bf(u1.w);
            frag[h][s] = fr;
        }
    }

    float fsum = 0.f;
    #pragma unroll
    for (int fi = 0; fi < 2; ++fi) {
        #pragma unroll
        for (int fj = 0; fj < 2; ++fj) {
            f32x16 a = fzero();
            #pragma unroll
            for (int s = 0; s < 4; ++s)
                a = __builtin_amdgcn_mfma_f32_32x32x16_bf16(frag[fi][s], frag[fj][s], a, 0, 0, 0);
            #pragma unroll
            for (int r = 0; r < 16; ++r) {
                const int row = fi * 32 + (r & 3) + 8 * (r >> 2) + 4 * hi;
                const int col = fj * 32 + li;
                const float d = a[r] - ((row == col) ? 1.0f : 0.0f);
                fsum = fmaf(d, d, fsum);
            }
        }
    }

    #pragma unroll
    for (int off = 32; off > 0; off >>= 1)
        fsum += __shfl_down(fsum, off, 64);
    if (lane == 0)
        atomicAdd(out, (0.1f / (float)BB) * sqrtf(fsum));
}

extern "C" void kernel_launch(void* const* d_in, const int* in_sizes, int n_in,
                              void* d_out, int out_size, void* d_ws, size_t ws_size,
                              hipStream_t stream)
{
    const float* pred  = (const float*)d_in[0];
    const float* gt    = (const float*)d_in[1];
    const float* trans = (const float*)d_in[2];
    float* out = (float*)d_out;

    hipMemsetAsync(out, 0, sizeof(float), stream);
    reg_kernel<<<dim3(BB), dim3(64), 0, stream>>>(trans, out);
    chamfer_kernel<<<dim3(NN / 256, BB, 2), dim3(256), 0, stream>>>(pred, gt, out);
}